// Round 21
// baseline (259.802 us; speedup 1.0000x reference)
//
#include <hip/hip_runtime.h>
#include <hip/hip_bf16.h>
#include <math.h>

#define B_      2
#define S_      2048
#define D_      2048
#define H_      16
#define QRANK   768
#define KVRANK  256
#define ROWS    (B_ * S_)   // 4096
#define CC_LD   1152        // cq(768) | ckv(256) | kr_raw(32) | pad(96)
#define QQ_LD   1536        // qn(1024) | qr(512)

typedef __attribute__((ext_vector_type(8))) short short8;
typedef __attribute__((ext_vector_type(4))) float f32x4;
typedef __attribute__((ext_vector_type(4))) unsigned short ushort4v;
typedef __attribute__((ext_vector_type(2))) unsigned int uint2v;

__device__ __forceinline__ float bf2f(unsigned short u) {
  return __uint_as_float(((unsigned)u) << 16);
}
__device__ __forceinline__ unsigned short f2bf(float f) {  // RNE
  unsigned u = __float_as_uint(f);
  return (unsigned short)((u + 0x7fffu + ((u >> 16) & 1u)) >> 16);
}
__device__ __forceinline__ unsigned cvtpk_bf16(float lo, float hi) {
  unsigned r;
  asm("v_cvt_pk_bf16_f32 %0, %1, %2" : "=v"(r) : "v"(lo), "v"(hi));
  return r;
}
__device__ __forceinline__ void glds16(const unsigned short* g, unsigned short* l) {
  __builtin_amdgcn_global_load_lds(
      (const __attribute__((address_space(1))) unsigned int*)g,
      (__attribute__((address_space(3))) unsigned int*)l, 16, 0, 0);
}

// ---------------------------------------------------------------------------
// Batched transpose+cast: 8 jobs in one launch. in [R][C] f32 -> out [C][R] bf16.
// ---------------------------------------------------------------------------
struct TJobs {
  const float* in[8];
  unsigned short* out[8];
  int R[8], C[8], start[8];
};
__global__ __launch_bounds__(256) void transpose_cast_batch(TJobs j) {
  __shared__ unsigned short t[32][33];
  const int bid = blockIdx.x;
  int k = 0;
#pragma unroll
  for (int i = 1; i < 8; ++i)
    if (bid >= j.start[i]) k = i;
  const float* in = j.in[k];
  unsigned short* out = j.out[k];
  const int R = j.R[k], C = j.C[k];
  const int lb = bid - j.start[k];
  const int nbx = C >> 5;
  const int c0 = (lb % nbx) * 32, r0 = (lb / nbx) * 32;
  const int tx = threadIdx.x & 31, ty = threadIdx.x >> 5;
#pragma unroll
  for (int i = 0; i < 32; i += 8)
    t[ty + i][tx] = f2bf(in[(size_t)(r0 + ty + i) * C + c0 + tx]);
  __syncthreads();
#pragma unroll
  for (int i = 0; i < 32; i += 8)
    out[(size_t)(c0 + ty + i) * R + r0 + tx] = t[tx][ty + i];
}

// ---------------------------------------------------------------------------
// bf16 MFMA GEMM (TN): A [M][K] (row stride lda), Bt [N][K] (row stride ldb),
// C [M][N]. c_mode: 0 = f32 out, 1 = bf16 out, 2 = bf16 out + fused RoPE on
// global cols >= 1024. a_f32: A is fp32; staging casts to bf16 in-flight.
// Tile BM=64 x BN=128, BK=64; 256 thr = 4 waves. XOR swizzle on global src.
// XCD-aware tile remap (T1): requires (nbx*nby)%8==0 (all grids obey).
// ---------------------------------------------------------------------------
__global__ __launch_bounds__(256) void gemm_bf16(const unsigned short* __restrict__ A,
                                                 int lda,
                                                 const unsigned short* __restrict__ Bt,
                                                 int ldb,
                                                 void* __restrict__ Cv,
                                                 int M, int N, int K, int c_mode,
                                                 int a_f32) {
  __shared__ unsigned short As[64 * 64];    // 8 KB
  __shared__ unsigned short Bs[128 * 64];   // 16 KB
  const int tid = threadIdx.x;
  const int lane = tid & 63;
  const int wave = tid >> 6;
  const int wm = (wave >> 1) << 5;   // 0 / 32
  const int wn = (wave & 1) << 6;    // 0 / 64

  // ---- T1 remap: linear id -> (m0, n0) ----
  const int nbx = gridDim.x;
  const int nb = nbx * gridDim.y;
  const int bidl = blockIdx.y * nbx + blockIdx.x;
  const int qn = nb >> 3;
  const int logical = (bidl & 7) * qn + (bidl >> 3);
  const int bandsz = nbx << 3;
  const int band = logical / bandsz;
  const int pp = logical - band * bandsz;
  const int m0 = (band * 8 + (pp & 7)) * 64;
  const int n0 = (pp >> 3) * 128;

  // ---- staging geometry ----
  const int sr8 = lane >> 3, sg = lane & 7;
  size_t a_src[2], b_src[4];
  unsigned short* a_dst[2];
  unsigned short* b_dst[4];
  unsigned short* a_wdst[2];
#pragma unroll
  for (int c = 0; c < 2; ++c) {
    const int row = wave * 16 + c * 8 + sr8;
    a_src[c] = (size_t)(m0 + row) * lda + ((sg ^ (row & 7)) << 3);
    a_dst[c] = &As[(wave * 16 + c * 8) * 64];
    a_wdst[c] = &As[row * 64 + sg * 8];
  }
#pragma unroll
  for (int c = 0; c < 4; ++c) {
    const int row = wave * 32 + c * 8 + sr8;
    b_src[c] = (size_t)(n0 + row) * ldb + ((sg ^ (row & 7)) << 3);
    b_dst[c] = &Bs[(wave * 32 + c * 8) * 64];
  }
  const float* Af = (const float*)A;

  // ---- fragment read byte-offsets ----
  const int frow = lane & 15, fg = lane >> 4;
  int a_roff[2][2], b_roff[4][2];
#pragma unroll
  for (int m = 0; m < 2; ++m) {
    const int r = wm + m * 16 + frow;
#pragma unroll
    for (int kk = 0; kk < 2; ++kk)
      a_roff[m][kk] = r * 128 + (((kk * 4 + fg) ^ (r & 7)) << 4);
  }
#pragma unroll
  for (int n = 0; n < 4; ++n) {
    const int r = wn + n * 16 + frow;
#pragma unroll
    for (int kk = 0; kk < 2; ++kk)
      b_roff[n][kk] = r * 128 + (((kk * 4 + fg) ^ (r & 7)) << 4);
  }

  f32x4 acc[2][4];
#pragma unroll
  for (int m = 0; m < 2; ++m)
#pragma unroll
    for (int n = 0; n < 4; ++n) acc[m][n] = (f32x4){0.f, 0.f, 0.f, 0.f};

  for (int k0 = 0; k0 < K; k0 += 64) {
    float4 u0[2], u1[2];
    if (a_f32) {
#pragma unroll
      for (int c = 0; c < 2; ++c) {
        u0[c] = *(const float4*)&Af[a_src[c] + k0];
        u1[c] = *(const float4*)&Af[a_src[c] + k0 + 4];
      }
    }
    __syncthreads();   // prior iteration's LDS reads complete
    if (a_f32) {
#pragma unroll
      for (int c = 0; c < 2; ++c) {
        uint4 pk;
        pk.x = cvtpk_bf16(u0[c].x, u0[c].y);
        pk.y = cvtpk_bf16(u0[c].z, u0[c].w);
        pk.z = cvtpk_bf16(u1[c].x, u1[c].y);
        pk.w = cvtpk_bf16(u1[c].z, u1[c].w);
        *(uint4*)a_wdst[c] = pk;
      }
    } else {
#pragma unroll
      for (int c = 0; c < 2; ++c) glds16(A + a_src[c] + k0, a_dst[c]);
    }
#pragma unroll
    for (int c = 0; c < 4; ++c) glds16(Bt + b_src[c] + k0, b_dst[c]);
    __syncthreads();   // drains vmcnt + lgkm before reads
#pragma unroll
    for (int kk = 0; kk < 2; ++kk) {
      short8 af[2], bfr[4];
#pragma unroll
      for (int m = 0; m < 2; ++m) af[m] = *(const short8*)((const char*)As + a_roff[m][kk]);
#pragma unroll
      for (int n = 0; n < 4; ++n) bfr[n] = *(const short8*)((const char*)Bs + b_roff[n][kk]);
#pragma unroll
      for (int m = 0; m < 2; ++m)
#pragma unroll
        for (int n = 0; n < 4; ++n)
          acc[m][n] = __builtin_amdgcn_mfma_f32_16x16x32_bf16(af[m], bfr[n], acc[m][n], 0, 0, 0);
    }
  }

  const int crow = (lane >> 4) * 4;
  const int ccol = lane & 15;
  if (c_mode != 0) {
    unsigned short* Cb = (unsigned short*)Cv;
    const bool do_rope = (c_mode == 2) && (n0 >= 1024);
#pragma unroll
    for (int m = 0; m < 2; ++m)
#pragma unroll
      for (int n = 0; n < 4; ++n)
#pragma unroll
        for (int r = 0; r < 4; ++r) {
          float v = acc[m][n][r];
          if (do_rope) {
            float other = __shfl_xor(v, 1, 64);
            const int i = (((n & 1) << 4) + ccol) >> 1;
            float freq = exp2f(-0.8304820237218406f * (float)i);
            const int pos = (m0 + wm + m * 16 + crow + r) & (S_ - 1);
            float cth = cosf((float)pos * freq);
            v = (ccol & 1) ? (other + v) * cth : (v - other) * cth;
          }
          Cb[(size_t)(m0 + wm + m * 16 + crow + r) * N + n0 + wn + n * 16 + ccol] = f2bf(v);
        }
  } else {
    float* Cf = (float*)Cv;
#pragma unroll
    for (int m = 0; m < 2; ++m)
#pragma unroll
      for (int n = 0; n < 4; ++n)
#pragma unroll
        for (int r = 0; r < 4; ++r)
          Cf[(size_t)(m0 + wm + m * 16 + crow + r) * N + n0 + wn + n * 16 + ccol] =
              acc[m][n][r];
  }
}

// ---------------------------------------------------------------------------
// Fused per-row post-processing of cc (rope(kr) + both rmsnorms)
// ---------------------------------------------------------------------------
__global__ __launch_bounds__(256) void prep_cc(unsigned short* __restrict__ cc,
                                               const float* __restrict__ qg,
                                               const float* __restrict__ kvg,
                                               unsigned short* __restrict__ krb) {
  const int row = blockIdx.x;
  unsigned short* p = cc + (size_t)row * CC_LD;
  const int tid = threadIdx.x;
  if (tid < 16) {
    const int i = tid;
    const int pos = row & (S_ - 1);
    float freq = exp2f(-0.8304820237218406f * (float)i);
    float c = cosf((float)pos * freq);
    unsigned v = *(const unsigned*)(p + 1024 + 2 * i);
    float xr = bf2f((unsigned short)(v & 0xffffu)) * (1.0f / 16.0f);
    float xi = bf2f((unsigned short)(v >> 16)) * (1.0f / 16.0f);
    *(unsigned*)(krb + (size_t)row * 32 + 2 * i) =
        (unsigned)f2bf((xr - xi) * c) | ((unsigned)f2bf((xr + xi) * c) << 16);
  }
  __shared__ float w1[4], w2[4];
  float ss = 0.f;
  for (int c = tid; c < QRANK; c += 256) { float v = bf2f(p[c]); ss += v * v; }
  float s2 = 0.f;
  { float v = bf2f(p[QRANK + tid]); s2 = v * v; }
#pragma unroll
  for (int off = 32; off >= 1; off >>= 1) {
    ss += __shfl_xor(ss, off, 64);
    s2 += __shfl_xor(s2, off, 64);
  }
  if ((tid & 63) == 0) { w1[tid >> 6] = ss; w2[tid >> 6] = s2; }
  __syncthreads();
  float r1 = rsqrtf((w1[0] + w1[1] + w1[2] + w1[3]) * (1.0f / QRANK) + 1e-6f);
  float r2 = rsqrtf((w2[0] + w2[1] + w2[2] + w2[3]) * (1.0f / KVRANK) + 1e-6f);
  for (int c = tid; c < QRANK; c += 256) p[c] = f2bf(bf2f(p[c]) * r1 * qg[c]);
  { int c = QRANK + tid; p[c] = f2bf(bf2f(p[c]) * r2 * kvg[tid]); }
}

// ---------------------------------------------------------------------------
// MFMA flash attention v3 (barrier-free): dual-tile 8-wave blocks, lane-local
// softmax, T13, KVBLK=128. K/V/kr are read DIRECTLY from global per fragment
// (XCD swizzle keeps each XCD's 4-head K/V working set ~2 MB L2-resident;
// every fragment load consumes full 64B lines). No Ks/Vt LDS, no ISSUE/COMMIT,
// ZERO __syncthreads — each wave loops to its OWN causal limit and free-runs.
// Ps stays in LDS (wave-private rows; wave_barrier only). LDS 34.8 KB.
// ---------------------------------------------------------------------------
#define PS_ST 136

__global__ __launch_bounds__(512, 4) void attn_mfma(
    const unsigned short* __restrict__ qq,   // [4096][1536]: qn | qr
    const unsigned short* __restrict__ knb,  // [4096][1024]
    const unsigned short* __restrict__ krb,  // [4096][32]
    const unsigned short* __restrict__ vvT,  // [1024][4096]: [h*64+d][b*2048+s]
    unsigned short* __restrict__ aob) {      // [4096][1024]
  __shared__ unsigned short Ps[128 * PS_ST];  // 34.8 KB (wave-private rows)
  const int tid = threadIdx.x;
  const int lane = tid & 63;
  const int wave = tid >> 6;          // 0..7
  const int grp = wave >> 2;          // 0: tile p, 1: tile 31-p
  const int qw = wave & 3;
  // XCD swizzle + CU balance (R18-proven mapping)
  const int bid = blockIdx.x;
  const int bh = ((bid >> 7) << 3) | (bid & 7);
  const int praw = (bid >> 3) & 15;
  const int p = (bid >= 256) ? (15 - praw) : praw;
  const int b = bh >> 4, h = bh & 15;
  const size_t rowbase = (size_t)b * S_;
  const int frow = lane & 15, fg = lane >> 4;
  const int ccol = frow;
  const int crow = fg * 4;
  const float C2 = 0.10206207261596575f * 1.4426950408889634f;  // scale*log2(e)

  const int q0 = (grp ? (31 - p) : p) * 64;
  const int nkt = (q0 >> 7) + 1;       // own causal limit per wave-group

  // Q fragments in registers (one q-row per lane, 96 dims)
  const size_t qrow = rowbase + q0 + qw * 16 + frow;
  short8 qf0 = *(const short8*)&qq[qrow * QQ_LD + (h << 6) + fg * 8];
  short8 qf1 = *(const short8*)&qq[qrow * QQ_LD + (h << 6) + 32 + fg * 8];
  short8 qf2 = *(const short8*)&qq[qrow * QQ_LD + 1024 + (h << 5) + fg * 8];

  float m = -1e30f, l = 0.f;
  f32x4 acc_o[4];
#pragma unroll
  for (int n = 0; n < 4; ++n) acc_o[n] = (f32x4){0.f, 0.f, 0.f, 0.f};

  for (int kt = 0; kt < nkt; ++kt) {
    const int k0 = kt << 7;
    // ---- QK^T (A=K direct-from-global, B=Q-regs) ----
    f32x4 sa[8];
#pragma unroll
    for (int n = 0; n < 8; ++n) sa[n] = (f32x4){0.f, 0.f, 0.f, 0.f};
    __builtin_amdgcn_s_setprio(1);
#pragma unroll
    for (int n = 0; n < 8; ++n) {
      const size_t krow = rowbase + k0 + n * 16 + frow;
      short8 bk0 = *(const short8*)&knb[krow * 1024 + (h << 6) + fg * 8];
      short8 bk1 = *(const short8*)&knb[krow * 1024 + (h << 6) + 32 + fg * 8];
      short8 bk2 = *(const short8*)&krb[krow * 32 + fg * 8];
      sa[n] = __builtin_amdgcn_mfma_f32_16x16x32_bf16(bk0, qf0, sa[n], 0, 0, 0);
      sa[n] = __builtin_amdgcn_mfma_f32_16x16x32_bf16(bk1, qf1, sa[n], 0, 0, 0);
      sa[n] = __builtin_amdgcn_mfma_f32_16x16x32_bf16(bk2, qf2, sa[n], 0, 0, 0);
    }
    __builtin_amdgcn_s_setprio(0);
    if (k0 + 127 > q0) {  // causal mask (global indices)
      const int qg = q0 + qw * 16 + ccol;
#pragma unroll
      for (int n = 0; n < 8; ++n)
#pragma unroll
        for (int r = 0; r < 4; ++r)
          if (k0 + n * 16 + crow + r > qg) sa[n][r] = -1e30f;
    }

    // ---- online softmax: in-lane over 32 + 2 shfl; T13 defer-max ----
    float mx = sa[0][0];
#pragma unroll
    for (int n = 0; n < 8; ++n)
#pragma unroll
      for (int r = 0; r < 4; ++r) mx = fmaxf(mx, sa[n][r]);
    mx = fmaxf(mx, __shfl_xor(mx, 16, 64));
    mx = fmaxf(mx, __shfl_xor(mx, 32, 64));

    if (!__all((mx - m) * C2 <= 8.0f)) {
      float mn = fmaxf(m, mx);
      float ra = exp2f((m - mn) * C2);
      m = mn;
      l *= ra;
#pragma unroll
      for (int n = 0; n < 4; ++n) {
        acc_o[n][0] *= ra; acc_o[n][1] *= ra;
        acc_o[n][2] *= ra; acc_o[n][3] *= ra;
      }
    }
    const float mC2 = m * C2;
    float rs = 0.f;
    const int prow = ((grp << 6) + qw * 16 + ccol) * PS_ST;
#pragma unroll
    for (int n = 0; n < 8; ++n) {
      float p0 = exp2f(fmaf(sa[n][0], C2, -mC2));
      float p1 = exp2f(fmaf(sa[n][1], C2, -mC2));
      float p2 = exp2f(fmaf(sa[n][2], C2, -mC2));
      float p3 = exp2f(fmaf(sa[n][3], C2, -mC2));
      rs += (p0 + p1) + (p2 + p3);
      uint2v pk;
      pk.x = cvtpk_bf16(p0, p1);
      pk.y = cvtpk_bf16(p2, p3);
      *(uint2v*)&Ps[prow + n * 16 + crow] = pk;
    }
    rs += __shfl_xor(rs, 16, 64);
    rs += __shfl_xor(rs, 32, 64);
    l += rs;
    __builtin_amdgcn_wave_barrier();

    // ---- PV (A=V^T direct-from-global, B=P from wave-private LDS) ----
    __builtin_amdgcn_s_setprio(1);
#pragma unroll
    for (int c = 0; c < 4; ++c) {
      short8 ap = *(const short8*)&Ps[((grp << 6) + qw * 16 + frow) * PS_ST + c * 32 + fg * 8];
#pragma unroll
      for (int n = 0; n < 4; ++n) {
        short8 bv = *(const short8*)&vvT[(size_t)((h << 6) + n * 16 + frow) * 4096 +
                                         b * S_ + k0 + c * 32 + fg * 8];
        acc_o[n] = __builtin_amdgcn_mfma_f32_16x16x32_bf16(bv, ap, acc_o[n], 0, 0, 0);
      }
    }
    __builtin_amdgcn_s_setprio(0);
    __builtin_amdgcn_wave_barrier();
  }

  const float inv = 1.f / l;
  const size_t obase = (size_t)(rowbase + q0 + qw * 16 + ccol) * 1024 + (h << 6);
#pragma unroll
  for (int n = 0; n < 4; ++n) {
    uint2v pk;
    pk.x = cvtpk_bf16(acc_o[n][0] * inv, acc_o[n][1] * inv);
    pk.y = cvtpk_bf16(acc_o[n][2] * inv, acc_o[n][3] * inv);
    *(uint2v*)&aob[obase + n * 16 + crow] = pk;
  }
}

// ---------------------------------------------------------------------------
extern "C" void kernel_launch(void* const* d_in, const int* in_sizes, int n_in,
                              void* d_out, int out_size, void* d_ws, size_t ws_size,
                              hipStream_t stream) {
  const float* x        = (const float*)d_in[0];
  const float* w_cq     = (const float*)d_in[1];
  const float* w_q_nope = (const float*)d_in[2];
  const float* w_q_rope = (const float*)d_in[3];
  const float* q_g      = (const float*)d_in[4];
  const float* w_ckv    = (const float*)d_in[5];
  const float* w_k_nope = (const float*)d_in[6];
  const float* w_v      = (const float*)d_in[7];
  const float* kv_g     = (const float*)d_in[8];
  const float* w_k_rope = (const float*)d_in[9];
  const float* w_proj   = (const float*)d_in[10];
  float* out = (float*)d_out;

  // ---- workspace layout (bf16) ----
  char* w = (char*)d_ws;
  unsigned short* cc    = (unsigned short*)w; w += (size_t)ROWS * CC_LD * 2;   // cq|ckv|kr
  unsigned short* qq    = (unsigned short*)w; w += (size_t)ROWS * QQ_LD * 2;   // qn|qr
  unsigned short* knb   = (unsigned short*)w; w += (size_t)ROWS * 1024 * 2;
  unsigned short* vvT   = (unsigned short*)w; w += (size_t)1024 * ROWS * 2;
  unsigned short* krb   = (unsigned short*)w; w += (size_t)ROWS * 32 * 2;
  unsigned short* aob   = (unsigned short*)w; w += (size_t)ROWS * 1024 * 2;
  unsigned short* wAll  = (unsigned short*)w; w += (size_t)CC_LD * 2048 * 2;   // wcqT|wckvT|wkrT|pad
  unsigned short* wqnT  = (unsigned short*)w; w += (size_t)1024 * QRANK * 2;
  unsigned short* wqrT  = (unsigned short*)w; w += (size_t)512 * QRANK * 2;    // adjacent to wqnT
  unsigned short* wknT  = (unsigned short*)w; w += (size_t)1024 * KVRANK * 2;
  unsigned short* wvT   = (unsigned short*)w; w += (size_t)1024 * KVRANK * 2;
  unsigned short* wprojT= (unsigned short*)w; w += (size_t)2048 * 1024 * 2;
  unsigned short* wcqT  = wAll;
  unsigned short* wckvT = wAll + (size_t)QRANK * 2048;
  unsigned short* wkrT  = wAll + (size_t)1024 * 2048;

  // ---- batched weight transposes ----
  TJobs tj;
  tj.in[0] = w_cq;     tj.out[0] = wcqT;   tj.R[0] = 2048; tj.C[0] = QRANK;  tj.start[0] = 0;
  tj.in[1] = w_q_nope; tj.out[1] = wqnT;   tj.R[1] = QRANK;tj.C[1] = 1024;   tj.start[1] = 1536;
  tj.in[2] = w_q_rope; tj.out[2] = wqrT;   tj.R[2] = QRANK;tj.C[2] = 512;    tj.start[2] = 2304;
  tj.in[3] = w_ckv;    tj.out[3] = wckvT;  tj.R[3] = 2048; tj.C[3] = KVRANK; tj.start[3] = 2688;
  tj.in[4] = w_k_nope; tj.out[4] = wknT;   tj.R[4] = KVRANK;tj.C[4] = 1024;  tj.start[4] = 3200;
  tj.in[5] = w_v;      tj.out[5] = wvT;    tj.R[5] = KVRANK;tj.C[5] = 1024;  tj.start[5] = 3456;
  tj.in[6] = w_proj;   tj.out[6] = wprojT; tj.R[6] = 1024; tj.C[6] = 2048;   tj.start[6] = 3712;
  tj.in[7] = w_k_rope; tj.out[7] = wkrT;   tj.R[7] = 2048; tj.C[7] = 32;     tj.start[7] = 5760;
  transpose_cast_batch<<<5824, 256, 0, stream>>>(tj);

  // ---- cc = x @ [w_cq | w_ckv | w_k_rope | pad]  (576 blocks; A=f32 fused cast) ----
  gemm_bf16<<<dim3(CC_LD / 128, ROWS / 64), 256, 0, stream>>>(
      (const unsigned short*)x, 2048, wAll, 2048, cc, ROWS, CC_LD, 2048, 1, 1);
  // fused: rope(kr) + rmsnorm(cq)+rmsnorm(ckv)
  prep_cc<<<ROWS, 256, 0, stream>>>(cc, q_g, kv_g, krb);

  // ---- qq = cq @ [w_q_nope | w_q_rope]  (768 blocks), RoPE fused ----
  gemm_bf16<<<dim3(QQ_LD / 128, ROWS / 64), 256, 0, stream>>>(
      cc, CC_LD, wqnT, QRANK, qq, ROWS, QQ_LD, QRANK, 2, 0);

  // ---- kn = ckv @ w_k_nope  (512 blocks) ----
  gemm_bf16<<<dim3(1024 / 128, ROWS / 64), 256, 0, stream>>>(
      cc + QRANK, CC_LD, wknT, KVRANK, knb, ROWS, 1024, KVRANK, 1, 0);
  // ---- vvT = w_v^T @ ckv^T  (512 blocks; [d][token] directly) ----
  gemm_bf16<<<dim3(ROWS / 128, 1024 / 64), 256, 0, stream>>>(
      wvT, KVRANK, cc + QRANK, CC_LD, vvT, 1024, ROWS, KVRANK, 1, 0);

  // ---- attention (v3: barrier-free, direct-from-L2 K/V) ----
  attn_mfma<<<512, 512, 0, stream>>>(qq, knb, krb, vvT, aob);

  // ---- output projection (1024 blocks) ----
  gemm_bf16<<<dim3(2048 / 128, ROWS / 64), 256, 0, stream>>>(
      aob, 1024, wprojT, 1024, out, ROWS, 2048, 1024, 0, 0);
}

// Round 22
// 166.441 us; speedup vs baseline: 1.5609x; 1.5609x over previous
//
#include <hip/hip_runtime.h>
#include <hip/hip_bf16.h>
#include <math.h>

#define B_      2
#define S_      2048
#define D_      2048
#define H_      16
#define QRANK   768
#define KVRANK  256
#define ROWS    (B_ * S_)   // 4096
#define CC_LD   1152        // cq(768) | ckv(256) | kr_raw(32) | pad(96)
#define QQ_LD   1536        // qn(1024) | qr(512)

typedef __attribute__((ext_vector_type(8))) short short8;
typedef __attribute__((ext_vector_type(4))) float f32x4;
typedef __attribute__((ext_vector_type(4))) unsigned short ushort4v;
typedef __attribute__((ext_vector_type(2))) unsigned int uint2v;

__device__ __forceinline__ float bf2f(unsigned short u) {
  return __uint_as_float(((unsigned)u) << 16);
}
__device__ __forceinline__ unsigned short f2bf(float f) {  // RNE
  unsigned u = __float_as_uint(f);
  return (unsigned short)((u + 0x7fffu + ((u >> 16) & 1u)) >> 16);
}
__device__ __forceinline__ unsigned cvtpk_bf16(float lo, float hi) {
  unsigned r;
  asm("v_cvt_pk_bf16_f32 %0, %1, %2" : "=v"(r) : "v"(lo), "v"(hi));
  return r;
}
__device__ __forceinline__ void glds16(const unsigned short* g, unsigned short* l) {
  __builtin_amdgcn_global_load_lds(
      (const __attribute__((address_space(1))) unsigned int*)g,
      (__attribute__((address_space(3))) unsigned int*)l, 16, 0, 0);
}

// ---------------------------------------------------------------------------
// Batched transpose+cast: 8 jobs in one launch. in [R][C] f32 -> out [C][R] bf16.
// ---------------------------------------------------------------------------
struct TJobs {
  const float* in[8];
  unsigned short* out[8];
  int R[8], C[8], start[8];
};
__global__ __launch_bounds__(256) void transpose_cast_batch(TJobs j) {
  __shared__ unsigned short t[32][33];
  const int bid = blockIdx.x;
  int k = 0;
#pragma unroll
  for (int i = 1; i < 8; ++i)
    if (bid >= j.start[i]) k = i;
  const float* in = j.in[k];
  unsigned short* out = j.out[k];
  const int R = j.R[k], C = j.C[k];
  const int lb = bid - j.start[k];
  const int nbx = C >> 5;
  const int c0 = (lb % nbx) * 32, r0 = (lb / nbx) * 32;
  const int tx = threadIdx.x & 31, ty = threadIdx.x >> 5;
#pragma unroll
  for (int i = 0; i < 32; i += 8)
    t[ty + i][tx] = f2bf(in[(size_t)(r0 + ty + i) * C + c0 + tx]);
  __syncthreads();
#pragma unroll
  for (int i = 0; i < 32; i += 8)
    out[(size_t)(c0 + ty + i) * R + r0 + tx] = t[tx][ty + i];
}

// ---------------------------------------------------------------------------
// bf16 MFMA GEMM (TN): A [M][K] (row stride lda), Bt [N][K] (row stride ldb),
// C [M][N]. c_mode: 0 = f32 out, 1 = bf16 out, 2 = bf16 out + fused RoPE on
// global cols >= 1024. a_f32: A is fp32; staging casts to bf16 in-flight.
// Tile BM=64 x BN=128, BK=64; 256 thr = 4 waves. XOR swizzle on global src.
// XCD-aware tile remap (T1): requires (nbx*nby)%8==0 (all grids obey).
// ---------------------------------------------------------------------------
__global__ __launch_bounds__(256) void gemm_bf16(const unsigned short* __restrict__ A,
                                                 int lda,
                                                 const unsigned short* __restrict__ Bt,
                                                 int ldb,
                                                 void* __restrict__ Cv,
                                                 int M, int N, int K, int c_mode,
                                                 int a_f32) {
  __shared__ unsigned short As[64 * 64];    // 8 KB
  __shared__ unsigned short Bs[128 * 64];   // 16 KB
  const int tid = threadIdx.x;
  const int lane = tid & 63;
  const int wave = tid >> 6;
  const int wm = (wave >> 1) << 5;   // 0 / 32
  const int wn = (wave & 1) << 6;    // 0 / 64

  // ---- T1 remap: linear id -> (m0, n0) ----
  const int nbx = gridDim.x;
  const int nb = nbx * gridDim.y;
  const int bidl = blockIdx.y * nbx + blockIdx.x;
  const int qn = nb >> 3;
  const int logical = (bidl & 7) * qn + (bidl >> 3);
  const int bandsz = nbx << 3;
  const int band = logical / bandsz;
  const int pp = logical - band * bandsz;
  const int m0 = (band * 8 + (pp & 7)) * 64;
  const int n0 = (pp >> 3) * 128;

  // ---- staging geometry ----
  const int sr8 = lane >> 3, sg = lane & 7;
  size_t a_src[2], b_src[4];
  unsigned short* a_dst[2];
  unsigned short* b_dst[4];
  unsigned short* a_wdst[2];
#pragma unroll
  for (int c = 0; c < 2; ++c) {
    const int row = wave * 16 + c * 8 + sr8;
    a_src[c] = (size_t)(m0 + row) * lda + ((sg ^ (row & 7)) << 3);
    a_dst[c] = &As[(wave * 16 + c * 8) * 64];
    a_wdst[c] = &As[row * 64 + sg * 8];
  }
#pragma unroll
  for (int c = 0; c < 4; ++c) {
    const int row = wave * 32 + c * 8 + sr8;
    b_src[c] = (size_t)(n0 + row) * ldb + ((sg ^ (row & 7)) << 3);
    b_dst[c] = &Bs[(wave * 32 + c * 8) * 64];
  }
  const float* Af = (const float*)A;

  // ---- fragment read byte-offsets ----
  const int frow = lane & 15, fg = lane >> 4;
  int a_roff[2][2], b_roff[4][2];
#pragma unroll
  for (int m = 0; m < 2; ++m) {
    const int r = wm + m * 16 + frow;
#pragma unroll
    for (int kk = 0; kk < 2; ++kk)
      a_roff[m][kk] = r * 128 + (((kk * 4 + fg) ^ (r & 7)) << 4);
  }
#pragma unroll
  for (int n = 0; n < 4; ++n) {
    const int r = wn + n * 16 + frow;
#pragma unroll
    for (int kk = 0; kk < 2; ++kk)
      b_roff[n][kk] = r * 128 + (((kk * 4 + fg) ^ (r & 7)) << 4);
  }

  f32x4 acc[2][4];
#pragma unroll
  for (int m = 0; m < 2; ++m)
#pragma unroll
    for (int n = 0; n < 4; ++n) acc[m][n] = (f32x4){0.f, 0.f, 0.f, 0.f};

  for (int k0 = 0; k0 < K; k0 += 64) {
    float4 u0[2], u1[2];
    if (a_f32) {
#pragma unroll
      for (int c = 0; c < 2; ++c) {
        u0[c] = *(const float4*)&Af[a_src[c] + k0];
        u1[c] = *(const float4*)&Af[a_src[c] + k0 + 4];
      }
    }
    __syncthreads();   // prior iteration's LDS reads complete
    if (a_f32) {
#pragma unroll
      for (int c = 0; c < 2; ++c) {
        uint4 pk;
        pk.x = cvtpk_bf16(u0[c].x, u0[c].y);
        pk.y = cvtpk_bf16(u0[c].z, u0[c].w);
        pk.z = cvtpk_bf16(u1[c].x, u1[c].y);
        pk.w = cvtpk_bf16(u1[c].z, u1[c].w);
        *(uint4*)a_wdst[c] = pk;
      }
    } else {
#pragma unroll
      for (int c = 0; c < 2; ++c) glds16(A + a_src[c] + k0, a_dst[c]);
    }
#pragma unroll
    for (int c = 0; c < 4; ++c) glds16(Bt + b_src[c] + k0, b_dst[c]);
    __syncthreads();   // drains vmcnt + lgkm before reads
#pragma unroll
    for (int kk = 0; kk < 2; ++kk) {
      short8 af[2], bfr[4];
#pragma unroll
      for (int m = 0; m < 2; ++m) af[m] = *(const short8*)((const char*)As + a_roff[m][kk]);
#pragma unroll
      for (int n = 0; n < 4; ++n) bfr[n] = *(const short8*)((const char*)Bs + b_roff[n][kk]);
#pragma unroll
      for (int m = 0; m < 2; ++m)
#pragma unroll
        for (int n = 0; n < 4; ++n)
          acc[m][n] = __builtin_amdgcn_mfma_f32_16x16x32_bf16(af[m], bfr[n], acc[m][n], 0, 0, 0);
    }
  }

  const int crow = (lane >> 4) * 4;
  const int ccol = lane & 15;
  if (c_mode != 0) {
    unsigned short* Cb = (unsigned short*)Cv;
    const bool do_rope = (c_mode == 2) && (n0 >= 1024);
#pragma unroll
    for (int m = 0; m < 2; ++m)
#pragma unroll
      for (int n = 0; n < 4; ++n)
#pragma unroll
        for (int r = 0; r < 4; ++r) {
          float v = acc[m][n][r];
          if (do_rope) {
            float other = __shfl_xor(v, 1, 64);
            const int i = (((n & 1) << 4) + ccol) >> 1;
            float freq = exp2f(-0.8304820237218406f * (float)i);
            const int pos = (m0 + wm + m * 16 + crow + r) & (S_ - 1);
            float cth = cosf((float)pos * freq);
            v = (ccol & 1) ? (other + v) * cth : (v - other) * cth;
          }
          Cb[(size_t)(m0 + wm + m * 16 + crow + r) * N + n0 + wn + n * 16 + ccol] = f2bf(v);
        }
  } else {
    float* Cf = (float*)Cv;
#pragma unroll
    for (int m = 0; m < 2; ++m)
#pragma unroll
      for (int n = 0; n < 4; ++n)
#pragma unroll
        for (int r = 0; r < 4; ++r)
          Cf[(size_t)(m0 + wm + m * 16 + crow + r) * N + n0 + wn + n * 16 + ccol] =
              acc[m][n][r];
  }
}

// ---------------------------------------------------------------------------
// Fused per-row post-processing of cc (rope(kr) + both rmsnorms)
// ---------------------------------------------------------------------------
__global__ __launch_bounds__(256) void prep_cc(unsigned short* __restrict__ cc,
                                               const float* __restrict__ qg,
                                               const float* __restrict__ kvg,
                                               unsigned short* __restrict__ krb) {
  const int row = blockIdx.x;
  unsigned short* p = cc + (size_t)row * CC_LD;
  const int tid = threadIdx.x;
  if (tid < 16) {
    const int i = tid;
    const int pos = row & (S_ - 1);
    float freq = exp2f(-0.8304820237218406f * (float)i);
    float c = cosf((float)pos * freq);
    unsigned v = *(const unsigned*)(p + 1024 + 2 * i);
    float xr = bf2f((unsigned short)(v & 0xffffu)) * (1.0f / 16.0f);
    float xi = bf2f((unsigned short)(v >> 16)) * (1.0f / 16.0f);
    *(unsigned*)(krb + (size_t)row * 32 + 2 * i) =
        (unsigned)f2bf((xr - xi) * c) | ((unsigned)f2bf((xr + xi) * c) << 16);
  }
  __shared__ float w1[4], w2[4];
  float ss = 0.f;
  for (int c = tid; c < QRANK; c += 256) { float v = bf2f(p[c]); ss += v * v; }
  float s2 = 0.f;
  { float v = bf2f(p[QRANK + tid]); s2 = v * v; }
#pragma unroll
  for (int off = 32; off >= 1; off >>= 1) {
    ss += __shfl_xor(ss, off, 64);
    s2 += __shfl_xor(s2, off, 64);
  }
  if ((tid & 63) == 0) { w1[tid >> 6] = ss; w2[tid >> 6] = s2; }
  __syncthreads();
  float r1 = rsqrtf((w1[0] + w1[1] + w1[2] + w1[3]) * (1.0f / QRANK) + 1e-6f);
  float r2 = rsqrtf((w2[0] + w2[1] + w2[2] + w2[3]) * (1.0f / KVRANK) + 1e-6f);
  for (int c = tid; c < QRANK; c += 256) p[c] = f2bf(bf2f(p[c]) * r1 * qg[c]);
  { int c = QRANK + tid; p[c] = f2bf(bf2f(p[c]) * r2 * kvg[tid]); }
}

// ---------------------------------------------------------------------------
// MFMA flash attention (R18/R20-proven): dual-tile 8-wave blocks, lane-local
// softmax, T13, KVBLK=128, single-buffer 2-barrier staging (2 blocks/CU,
// staging SHARED between the two q-tiles), XCD swizzle + CU-balance
// complement (b=1 heads use p=15-praw -> per-CU stage count uniform at 49).
// NOTE: the reg-prefetch ISSUE (next tile) before compute is the latency-
// hiding mechanism; removing the barriers/staging (R21 v3) cost 2.6x.
// ---------------------------------------------------------------------------
#define KS_ST 104   // 96 data + pad (208B row)
#define VT_ST 136   // 128 data + pad (272B row)
#define PS_ST 136

__global__ __launch_bounds__(512, 4) void attn_mfma(
    const unsigned short* __restrict__ qq,   // [4096][1536]: qn | qr
    const unsigned short* __restrict__ knb,  // [4096][1024]
    const unsigned short* __restrict__ krb,  // [4096][32]
    const unsigned short* __restrict__ vvT,  // [1024][4096]: [h*64+d][b*2048+s]
    unsigned short* __restrict__ aob) {      // [4096][1024]
  __shared__ unsigned short Ks[128 * KS_ST];  // 26.6 KB
  __shared__ unsigned short Vt[64 * VT_ST];   // 17.4 KB
  __shared__ unsigned short Ps[128 * PS_ST];  // 34.8 KB
  const int tid = threadIdx.x;
  const int lane = tid & 63;
  const int wave = tid >> 6;          // 0..7
  const int grp = wave >> 2;          // 0: tile p, 1: tile 31-p
  const int qw = wave & 3;
  // XCD swizzle + CU balance
  const int bid = blockIdx.x;
  const int bh = ((bid >> 7) << 3) | (bid & 7);
  const int praw = (bid >> 3) & 15;
  const int p = (bid >= 256) ? (15 - praw) : praw;
  const int b = bh >> 4, h = bh & 15;
  const size_t rowbase = (size_t)b * S_;
  const int frow = lane & 15, fg = lane >> 4;
  const int ccol = frow;
  const int crow = fg * 4;
  const float C2 = 0.10206207261596575f * 1.4426950408889634f;  // scale*log2(e)

  const int q0 = (grp ? (31 - p) : p) * 64;
  const int nkt = (((31 - p) * 64 + 63) >> 7) + 1;  // k-tiles for the big tile

  // staging geometry (512 threads)
  const int k_r = tid >> 3, k_c = (tid & 7) * 8;
  const int r_r = tid >> 2, r_c = (tid & 3) * 8;

  // Q fragments in registers (one q-row per lane, 96 dims)
  const size_t qrow = rowbase + q0 + qw * 16 + frow;
  short8 qf0 = *(const short8*)&qq[qrow * QQ_LD + (h << 6) + fg * 8];
  short8 qf1 = *(const short8*)&qq[qrow * QQ_LD + (h << 6) + 32 + fg * 8];
  short8 qf2 = *(const short8*)&qq[qrow * QQ_LD + 1024 + (h << 5) + fg * 8];

  float m = -1e30f, l = 0.f;
  f32x4 acc_o[4];
#pragma unroll
  for (int n = 0; n < 4; ++n) acc_o[n] = (f32x4){0.f, 0.f, 0.f, 0.f};

  uint4 kreg0, kreg1, rreg, vreg0, vreg1;
  auto ISSUE = [&](int kt) {
    const int k0v = kt << 7;
    kreg0 = *(const uint4*)&knb[(size_t)(rowbase + k0v + k_r) * 1024 + (h << 6) + k_c];
    kreg1 = *(const uint4*)&knb[(size_t)(rowbase + k0v + k_r + 64) * 1024 + (h << 6) + k_c];
    rreg  = *(const uint4*)&krb[(size_t)(rowbase + k0v + r_r) * 32 + r_c];
    vreg0 = *(const uint4*)&vvT[(size_t)((h << 6) + k_r) * 4096 + b * S_ + k0v + k_c];
    vreg1 = *(const uint4*)&vvT[(size_t)((h << 6) + k_r) * 4096 + b * S_ + k0v + 64 + k_c];
  };
  auto COMMIT = [&]() {
    *(uint4*)&Ks[k_r * KS_ST + k_c] = kreg0;
    *(uint4*)&Ks[(k_r + 64) * KS_ST + k_c] = kreg1;
    *(uint4*)&Ks[r_r * KS_ST + 64 + r_c] = rreg;
    *(uint4*)&Vt[k_r * VT_ST + k_c] = vreg0;
    *(uint4*)&Vt[k_r * VT_ST + 64 + k_c] = vreg1;
  };

  ISSUE(0);
  COMMIT();
  __syncthreads();

  for (int kt = 0; kt < nkt; ++kt) {
    if (kt + 1 < nkt) ISSUE(kt + 1);     // loads in flight during compute
    const int k0 = kt << 7;
    if (k0 <= q0 + 63) {
      // ---- QK^T (A=K, B=Q-regs) -> S[q=ccol][k=n*16+crow+r], n=0..7 ----
      f32x4 sa[8];
#pragma unroll
      for (int n = 0; n < 8; ++n) sa[n] = (f32x4){0.f, 0.f, 0.f, 0.f};
      __builtin_amdgcn_s_setprio(1);
#pragma unroll
      for (int n = 0; n < 8; ++n) {
        short8 bk0 = *(const short8*)&Ks[(n * 16 + frow) * KS_ST + fg * 8];
        short8 bk1 = *(const short8*)&Ks[(n * 16 + frow) * KS_ST + 32 + fg * 8];
        short8 bk2 = *(const short8*)&Ks[(n * 16 + frow) * KS_ST + 64 + fg * 8];
        sa[n] = __builtin_amdgcn_mfma_f32_16x16x32_bf16(bk0, qf0, sa[n], 0, 0, 0);
        sa[n] = __builtin_amdgcn_mfma_f32_16x16x32_bf16(bk1, qf1, sa[n], 0, 0, 0);
        sa[n] = __builtin_amdgcn_mfma_f32_16x16x32_bf16(bk2, qf2, sa[n], 0, 0, 0);
      }
      __builtin_amdgcn_s_setprio(0);
      if (k0 + 127 > q0) {  // causal mask (global indices)
        const int qg = q0 + qw * 16 + ccol;
#pragma unroll
        for (int n = 0; n < 8; ++n)
#pragma unroll
          for (int r = 0; r < 4; ++r)
            if (k0 + n * 16 + crow + r > qg) sa[n][r] = -1e30f;
      }

      // ---- online softmax: in-lane over 32 + 2 shfl; T13 defer-max ----
      float mx = sa[0][0];
#pragma unroll
      for (int n = 0; n < 8; ++n)
#pragma unroll
        for (int r = 0; r < 4; ++r) mx = fmaxf(mx, sa[n][r]);
      mx = fmaxf(mx, __shfl_xor(mx, 16, 64));
      mx = fmaxf(mx, __shfl_xor(mx, 32, 64));

      if (!__all((mx - m) * C2 <= 8.0f)) {
        float mn = fmaxf(m, mx);
        float ra = exp2f((m - mn) * C2);
        m = mn;
        l *= ra;
#pragma unroll
        for (int n = 0; n < 4; ++n) {
          acc_o[n][0] *= ra; acc_o[n][1] *= ra;
          acc_o[n][2] *= ra; acc_o[n][3] *= ra;
        }
      }
      const float mC2 = m * C2;
      float rs = 0.f;
      const int prow = ((grp << 6) + qw * 16 + ccol) * PS_ST;
#pragma unroll
      for (int n = 0; n < 8; ++n) {
        float p0 = exp2f(fmaf(sa[n][0], C2, -mC2));
        float p1 = exp2f(fmaf(sa[n][1], C2, -mC2));
        float p2 = exp2f(fmaf(sa[n][2], C2, -mC2));
        float p3 = exp2f(fmaf(sa[n][3], C2, -mC2));
        rs += (p0 + p1) + (p2 + p3);
        uint2v pk;
        pk.x = cvtpk_bf16(p0, p1);
        pk.y = cvtpk_bf16(p2, p3);
        *(uint2v*)&Ps[prow + n * 16 + crow] = pk;
      }
      rs += __shfl_xor(rs, 16, 64);
      rs += __shfl_xor(rs, 32, 64);
      l += rs;
      __builtin_amdgcn_wave_barrier();

      // ---- PV (A=V^T, B=P) -> O[q=ccol][d=n*16+crow+r] ----
      __builtin_amdgcn_s_setprio(1);
#pragma unroll
      for (int c = 0; c < 4; ++c) {
        short8 ap = *(const short8*)&Ps[((grp << 6) + qw * 16 + frow) * PS_ST + c * 32 + fg * 8];
#pragma unroll
        for (int n = 0; n < 4; ++n) {
          short8 bv = *(const short8*)&Vt[(n * 16 + frow) * VT_ST + c * 32 + fg * 8];
          acc_o[n] = __builtin_amdgcn_mfma_f32_16x16x32_bf16(bv, ap, acc_o[n], 0, 0, 0);
        }
      }
      __builtin_amdgcn_s_setprio(0);
      __builtin_amdgcn_wave_barrier();
    }
    __syncthreads();                      // all reads of Ks/Vt done
    if (kt + 1 < nkt) COMMIT();
    __syncthreads();
  }

  const float inv = 1.f / l;
  const size_t obase = (size_t)(rowbase + q0 + qw * 16 + ccol) * 1024 + (h << 6);
#pragma unroll
  for (int n = 0; n < 4; ++n) {
    uint2v pk;
    pk.x = cvtpk_bf16(acc_o[n][0] * inv, acc_o[n][1] * inv);
    pk.y = cvtpk_bf16(acc_o[n][2] * inv, acc_o[n][3] * inv);
    *(uint2v*)&aob[obase + n * 16 + crow] = pk;
  }
}

// ---------------------------------------------------------------------------
extern "C" void kernel_launch(void* const* d_in, const int* in_sizes, int n_in,
                              void* d_out, int out_size, void* d_ws, size_t ws_size,
                              hipStream_t stream) {
  const float* x        = (const float*)d_in[0];
  const float* w_cq     = (const float*)d_in[1];
  const float* w_q_nope = (const float*)d_in[2];
  const float* w_q_rope = (const float*)d_in[3];
  const float* q_g      = (const float*)d_in[4];
  const float* w_ckv    = (const float*)d_in[5];
  const float* w_k_nope = (const float*)d_in[6];
  const float* w_v      = (const float*)d_in[7];
  const float* kv_g     = (const float*)d_in[8];
  const float* w_k_rope = (const float*)d_in[9];
  const float* w_proj   = (const float*)d_in[10];
  float* out = (float*)d_out;

  // ---- workspace layout (bf16) ----
  char* w = (char*)d_ws;
  unsigned short* cc    = (unsigned short*)w; w += (size_t)ROWS * CC_LD * 2;   // cq|ckv|kr
  unsigned short* qq    = (unsigned short*)w; w += (size_t)ROWS * QQ_LD * 2;   // qn|qr
  unsigned short* knb   = (unsigned short*)w; w += (size_t)ROWS * 1024 * 2;
  unsigned short* vvT   = (unsigned short*)w; w += (size_t)1024 * ROWS * 2;
  unsigned short* krb   = (unsigned short*)w; w += (size_t)ROWS * 32 * 2;
  unsigned short* aob   = (unsigned short*)w; w += (size_t)ROWS * 1024 * 2;
  unsigned short* wAll  = (unsigned short*)w; w += (size_t)CC_LD * 2048 * 2;   // wcqT|wckvT|wkrT|pad
  unsigned short* wqnT  = (unsigned short*)w; w += (size_t)1024 * QRANK * 2;
  unsigned short* wqrT  = (unsigned short*)w; w += (size_t)512 * QRANK * 2;    // adjacent to wqnT
  unsigned short* wknT  = (unsigned short*)w; w += (size_t)1024 * KVRANK * 2;
  unsigned short* wvT   = (unsigned short*)w; w += (size_t)1024 * KVRANK * 2;
  unsigned short* wprojT= (unsigned short*)w; w += (size_t)2048 * 1024 * 2;
  unsigned short* wcqT  = wAll;
  unsigned short* wckvT = wAll + (size_t)QRANK * 2048;
  unsigned short* wkrT  = wAll + (size_t)1024 * 2048;

  // ---- batched weight transposes ----
  TJobs tj;
  tj.in[0] = w_cq;     tj.out[0] = wcqT;   tj.R[0] = 2048; tj.C[0] = QRANK;  tj.start[0] = 0;
  tj.in[1] = w_q_nope; tj.out[1] = wqnT;   tj.R[1] = QRANK;tj.C[1] = 1024;   tj.start[1] = 1536;
  tj.in[2] = w_q_rope; tj.out[2] = wqrT;   tj.R[2] = QRANK;tj.C[2] = 512;    tj.start[2] = 2304;
  tj.in[3] = w_ckv;    tj.out[3] = wckvT;  tj.R[3] = 2048; tj.C[3] = KVRANK; tj.start[3] = 2688;
  tj.in[4] = w_k_nope; tj.out[4] = wknT;   tj.R[4] = KVRANK;tj.C[4] = 1024;  tj.start[4] = 3200;
  tj.in[5] = w_v;      tj.out[5] = wvT;    tj.R[5] = KVRANK;tj.C[5] = 1024;  tj.start[5] = 3456;
  tj.in[6] = w_proj;   tj.out[6] = wprojT; tj.R[6] = 1024; tj.C[6] = 2048;   tj.start[6] = 3712;
  tj.in[7] = w_k_rope; tj.out[7] = wkrT;   tj.R[7] = 2048; tj.C[7] = 32;     tj.start[7] = 5760;
  transpose_cast_batch<<<5824, 256, 0, stream>>>(tj);

  // ---- cc = x @ [w_cq | w_ckv | w_k_rope | pad]  (576 blocks; A=f32 fused cast) ----
  gemm_bf16<<<dim3(CC_LD / 128, ROWS / 64), 256, 0, stream>>>(
      (const unsigned short*)x, 2048, wAll, 2048, cc, ROWS, CC_LD, 2048, 1, 1);
  // fused: rope(kr) + rmsnorm(cq)+rmsnorm(ckv)
  prep_cc<<<ROWS, 256, 0, stream>>>(cc, q_g, kv_g, krb);

  // ---- qq = cq @ [w_q_nope | w_q_rope]  (768 blocks), RoPE fused ----
  gemm_bf16<<<dim3(QQ_LD / 128, ROWS / 64), 256, 0, stream>>>(
      cc, CC_LD, wqnT, QRANK, qq, ROWS, QQ_LD, QRANK, 2, 0);

  // ---- kn = ckv @ w_k_nope  (512 blocks) ----
  gemm_bf16<<<dim3(1024 / 128, ROWS / 64), 256, 0, stream>>>(
      cc + QRANK, CC_LD, wknT, KVRANK, knb, ROWS, 1024, KVRANK, 1, 0);
  // ---- vvT = w_v^T @ ckv^T  (512 blocks; [d][token] directly) ----
  gemm_bf16<<<dim3(ROWS / 128, 1024 / 64), 256, 0, stream>>>(
      wvT, KVRANK, cc + QRANK, CC_LD, vvT, 1024, ROWS, KVRANK, 1, 0);

  // ---- attention (R20: dual-tile 8-wave, shared staging, XCD+CU balance) ----
  attn_mfma<<<512, 512, 0, stream>>>(qq, knb, krb, vvT, aob);

  // ---- output projection (1024 blocks) ----
  gemm_bf16<<<dim3(2048 / 128, ROWS / 64), 256, 0, stream>>>(
      aob, 1024, wprojT, 1024, out, ROWS, 2048, 1024, 0, 0);
}